// Round 2
// baseline (547.863 us; speedup 1.0000x reference)
//
#include <hip/hip_runtime.h>
#include <stdint.h>

// ---------------------------------------------------------------------------
// LlamaAttention forward, MI355X (gfx950), input-dtype-agnostic (bf16 or fp32)
//   x:(2,2048,2048) Wq/Wk/Wv/Wo:(2048,2048)  out:(2,2048,2048)
// Pipeline:
//   0) sniff_k: detect input dtype (bf16 vs fp32) -> flag in ws
//   1) convert x -> bf16 xb; convert+transpose W -> bf16 W^T
//   2) gemm_bt xb@W^T -> Q,K,V (bf16, fp32 accum)
//   3) transpose V per batch -> Vt (staged in d_out, dead before final GEMM)
//   4) flash attention (online softmax) -> Ab (aliases Q slots; race-free)
//   5) gemm_bt Ab@Wo^T -> d_out (fp32 or bf16 per flag)
// Workspace (u16 units, SLOT = 2048*2048 = 4194304):
//   0..1 xb | 2..5 WqT WkT WvT WoT | 6..7 Q(=Ab) | 8..9 K | 10..11 V
//   flag (int) at ws + 12*SLOT.  Total ~96 MB + 4 B.
// ---------------------------------------------------------------------------

typedef unsigned short u16;
typedef __attribute__((ext_vector_type(8))) short bf16x8;   // 8 bf16 = 4 VGPRs (MFMA A/B frag)
typedef __attribute__((ext_vector_type(4))) float f32x4;    // MFMA C/D frag
typedef __attribute__((ext_vector_type(4))) short short4v;  // 8-byte pack

__device__ __forceinline__ u16 f2bf(float f) {
  union { float f; uint32_t u; } v; v.f = f;
  return (u16)((v.u + 0x7fffu + ((v.u >> 16) & 1u)) >> 16);  // round-nearest-even
}

// ---- dtype sniffer: bf16 N(0,1)-ish data has ~100% sane exponents ---------
__global__ __launch_bounds__(256) void sniff_k(const u16* __restrict__ x,
                                               int* __restrict__ flag) {
  __shared__ int cnt;
  const int t = threadIdx.x;
  if (t == 0) cnt = 0;
  __syncthreads();
  int sane = 0;
#pragma unroll
  for (int i = 0; i < 16; ++i) {
    u16 u = x[t * 16 + i];
    int e = (u >> 7) & 0xff;
    sane += (e >= 90 && e <= 150) ? 1 : 0;
  }
  atomicAdd(&cnt, sane);
  __syncthreads();
  if (t == 0) *flag = (cnt >= 3700) ? 0 : 1;  // 0 = bf16, 1 = fp32
}

// ---- x conversion: fp32->bf16 or bf16 copy, 8 elems/thread ----------------
__global__ __launch_bounds__(256) void convert_x_k(const void* __restrict__ xin,
                                                   u16* __restrict__ xb,
                                                   const int* __restrict__ flag) {
  const int i = (blockIdx.x * 256 + threadIdx.x) * 8;
  if (*flag) {
    const float* xf = (const float*)xin;
    float4 a = *(const float4*)(xf + i);
    float4 b = *(const float4*)(xf + i + 4);
    bf16x8 o;
    o[0] = (short)f2bf(a.x); o[1] = (short)f2bf(a.y);
    o[2] = (short)f2bf(a.z); o[3] = (short)f2bf(a.w);
    o[4] = (short)f2bf(b.x); o[5] = (short)f2bf(b.y);
    o[6] = (short)f2bf(b.z); o[7] = (short)f2bf(b.w);
    *(bf16x8*)(xb + i) = o;
  } else {
    *(bf16x8*)(xb + i) = *(const bf16x8*)((const u16*)xin + i);
  }
}

// ---- weight convert + transpose: 2048x2048, 64x64 tiles, grid (32,32) -----
__global__ __launch_bounds__(256) void convert_transpose_k(const void* __restrict__ in,
                                                           u16* __restrict__ out,
                                                           const int* __restrict__ flag) {
  __shared__ u16 tile[64][66];  // word stride 33 (odd) -> conflict-free col reads
  const int tr = blockIdx.y, tc = blockIdx.x, t = threadIdx.x;
  const int isF32 = *flag;
  if (isF32) {
    const float* inf32 = (const float*)in;
#pragma unroll
    for (int i = 0; i < 16; ++i) {
      int idx = t + i * 256, r = idx >> 6, c = idx & 63;
      tile[r][c] = f2bf(inf32[(size_t)(tr * 64 + r) * 2048 + tc * 64 + c]);
    }
  } else {
    const u16* inb = (const u16*)in;
#pragma unroll
    for (int i = 0; i < 16; ++i) {
      int idx = t + i * 256, r = idx >> 6, c = idx & 63;
      tile[r][c] = inb[(size_t)(tr * 64 + r) * 2048 + tc * 64 + c];
    }
  }
  __syncthreads();
#pragma unroll
  for (int i = 0; i < 16; ++i) {
    int idx = t + i * 256, r = idx >> 6, c = idx & 63;
    out[(size_t)(tc * 64 + r) * 2048 + tr * 64 + c] = tile[c][r];
  }
}

// ---- 2048x2048 bf16 transpose, 64x64 tiles, grid (32,32,Z) ----------------
__global__ __launch_bounds__(256) void transpose_k(const u16* __restrict__ in,
                                                   u16* __restrict__ out) {
  __shared__ u16 tile[64][66];
  const size_t zoff = (size_t)blockIdx.z * 4194304u;
  in += zoff; out += zoff;
  const int tr = blockIdx.y, tc = blockIdx.x, t = threadIdx.x;
#pragma unroll
  for (int i = 0; i < 16; ++i) {
    int idx = t + i * 256, r = idx >> 6, c = idx & 63;
    tile[r][c] = in[(size_t)(tr * 64 + r) * 2048 + tc * 64 + c];
  }
  __syncthreads();
#pragma unroll
  for (int i = 0; i < 16; ++i) {
    int idx = t + i * 256, r = idx >> 6, c = idx & 63;
    out[(size_t)(tc * 64 + r) * 2048 + tr * 64 + c] = tile[c][r];
  }
}

// ---- C[M,N] = A[M,K] x Bt[N,K]^T, bf16 in, fp32 accum ---------------------
// 128x128 block tile, 4 waves of 64x64, BK=64, mfma_f32_16x16x32_bf16.
// flag==nullptr -> bf16 store; else *flag chooses fp32 (1) / bf16 (0) store.
__global__ __launch_bounds__(256) void gemm_bt(const u16* __restrict__ A,
                                               const u16* __restrict__ Bt,
                                               void* __restrict__ C,
                                               int M, int N, int K,
                                               const int* __restrict__ flag) {
  __shared__ u16 As[128][72];  // +8 pad keeps 16B align, 2-way banks (free)
  __shared__ u16 Bs[128][72];
  const int bx = blockIdx.x, by = blockIdx.y, t = threadIdx.x;
  const int wave = t >> 6, lane = t & 63;
  const int g = lane >> 4, lq = lane & 15;
  const int wr = wave >> 1, wc = wave & 1;
  const int srow = t >> 3, scol = (t & 7) * 8;

  f32x4 acc[4][4];
#pragma unroll
  for (int i = 0; i < 4; ++i)
#pragma unroll
    for (int j = 0; j < 4; ++j) acc[i][j] = f32x4{0.f, 0.f, 0.f, 0.f};

  for (int kb = 0; kb < K; kb += 64) {
    __syncthreads();
#pragma unroll
    for (int i = 0; i < 4; ++i) {
      int r = i * 32 + srow;
      *(bf16x8*)(&As[r][scol]) = *(const bf16x8*)(&A[(size_t)(by * 128 + r) * K + kb + scol]);
      *(bf16x8*)(&Bs[r][scol]) = *(const bf16x8*)(&Bt[(size_t)(bx * 128 + r) * K + kb + scol]);
    }
    __syncthreads();
#pragma unroll
    for (int ks = 0; ks < 2; ++ks) {
      bf16x8 af[4], bfr[4];
#pragma unroll
      for (int mt = 0; mt < 4; ++mt)
        af[mt] = *(const bf16x8*)(&As[wr * 64 + mt * 16 + lq][ks * 32 + g * 8]);
#pragma unroll
      for (int nt = 0; nt < 4; ++nt)
        bfr[nt] = *(const bf16x8*)(&Bs[wc * 64 + nt * 16 + lq][ks * 32 + g * 8]);
#pragma unroll
      for (int mt = 0; mt < 4; ++mt)
#pragma unroll
        for (int nt = 0; nt < 4; ++nt)
          acc[mt][nt] = __builtin_amdgcn_mfma_f32_16x16x32_bf16(af[mt], bfr[nt], acc[mt][nt], 0, 0, 0);
    }
  }
  // C/D layout: col = lane&15, row = (lane>>4)*4 + reg   [m89/m91]
  const int outF32 = flag ? *flag : 0;
#pragma unroll
  for (int mt = 0; mt < 4; ++mt)
#pragma unroll
    for (int nt = 0; nt < 4; ++nt)
#pragma unroll
      for (int j = 0; j < 4; ++j) {
        size_t row = (size_t)(by * 128 + wr * 64 + mt * 16 + g * 4 + j);
        size_t col = (size_t)(bx * 128 + wc * 64 + nt * 16 + lq);
        size_t idx = row * (size_t)N + col;
        if (outF32) ((float*)C)[idx] = acc[mt][nt][j];
        else ((u16*)C)[idx] = f2bf(acc[mt][nt][j]);
      }
}

// ---- flash attention ------------------------------------------------------
// grid (S/64=32, H=16, B=2), 256 threads. Wave w handles queries [qb*64+w*16,+16).
// S^T = K x Q^T (row stats need only shfl_xor 16/32); P via per-wave LDS
// (C-layout -> A-layout, m120 pattern); PV from transposed-V LDS tile.
__global__ __launch_bounds__(256) void attn_kernel(const u16* __restrict__ Q,
                                                   const u16* __restrict__ K,
                                                   const u16* __restrict__ Vt,
                                                   u16* __restrict__ O) {
  __shared__ u16 Ks[64][136];    // [key][dh]   (+8 pad)
  __shared__ u16 Vs[128][72];    // [dh][key]   (+8 pad)
  __shared__ u16 Ps[4][16][72];  // [wave][q][key] (+8 pad)

  const int qb = blockIdx.x, h = blockIdx.y, b = blockIdx.z;
  const int t = threadIdx.x, wave = t >> 6, lane = t & 63;
  const int g = lane >> 4, lq = lane & 15;

  const size_t qk_base = ((size_t)b * 2048) * 2048 + (size_t)h * 128;  // [b][s][h*128+dh]
  const size_t vt_base = ((size_t)b * 2048 + (size_t)h * 128) * 2048;  // [b][h*128+dh][s]

  // Q fragments (B operand of S^T): lane holds Q[q=lq][dh = kk*32 + g*8 + j]
  bf16x8 qf[4];
  {
    const u16* qp = Q + qk_base + (size_t)(qb * 64 + wave * 16 + lq) * 2048 + g * 8;
#pragma unroll
    for (int kk = 0; kk < 4; ++kk) qf[kk] = *(const bf16x8*)(qp + kk * 32);
  }

  f32x4 acc_o[8];
#pragma unroll
  for (int i = 0; i < 8; ++i) acc_o[i] = f32x4{0.f, 0.f, 0.f, 0.f};
  float m_run = -1e30f, l_run = 0.f;
  const float sc = 0.08838834764831845f * 1.4426950408889634f;  // 128^-0.5 * log2(e)

  for (int kb = 0; kb < 2048; kb += 64) {
    __syncthreads();
    {  // stage K tile 64x128
      const int srow = t >> 2, scol = (t & 3) * 32;
      const u16* kp = K + qk_base + (size_t)(kb + srow) * 2048 + scol;
      *(bf16x8*)(&Ks[srow][scol + 0]) = *(const bf16x8*)(kp + 0);
      *(bf16x8*)(&Ks[srow][scol + 8]) = *(const bf16x8*)(kp + 8);
      *(bf16x8*)(&Ks[srow][scol + 16]) = *(const bf16x8*)(kp + 16);
      *(bf16x8*)(&Ks[srow][scol + 24]) = *(const bf16x8*)(kp + 24);
    }
    {  // stage Vt tile 128x64
      const int drow = t >> 1, dcol = (t & 1) * 32;
      const u16* vp = Vt + vt_base + (size_t)drow * 2048 + kb + dcol;
      *(bf16x8*)(&Vs[drow][dcol + 0]) = *(const bf16x8*)(vp + 0);
      *(bf16x8*)(&Vs[drow][dcol + 8]) = *(const bf16x8*)(vp + 8);
      *(bf16x8*)(&Vs[drow][dcol + 16]) = *(const bf16x8*)(vp + 16);
      *(bf16x8*)(&Vs[drow][dcol + 24]) = *(const bf16x8*)(vp + 24);
    }
    __syncthreads();

    // S^T tiles: D[key = mt*16 + g*4 + reg][q = lq]
    f32x4 st[4];
#pragma unroll
    for (int mt = 0; mt < 4; ++mt) st[mt] = f32x4{0.f, 0.f, 0.f, 0.f};
#pragma unroll
    for (int kk = 0; kk < 4; ++kk)
#pragma unroll
      for (int mt = 0; mt < 4; ++mt) {
        bf16x8 af = *(const bf16x8*)(&Ks[mt * 16 + lq][kk * 32 + g * 8]);
        st[mt] = __builtin_amdgcn_mfma_f32_16x16x32_bf16(af, qf[kk], st[mt], 0, 0, 0);
      }

    // online softmax for query lq (16 keys/lane; reduce across the 4 g-lanes)
    float tmax = -1e30f;
#pragma unroll
    for (int mt = 0; mt < 4; ++mt)
#pragma unroll
      for (int j = 0; j < 4; ++j) tmax = fmaxf(tmax, st[mt][j]);
    tmax = fmaxf(tmax, __shfl_xor(tmax, 16));
    tmax = fmaxf(tmax, __shfl_xor(tmax, 32));
    const float m_new = fmaxf(m_run, tmax);

    float lsum = 0.f;
    u16 pb[4][4];
#pragma unroll
    for (int mt = 0; mt < 4; ++mt)
#pragma unroll
      for (int j = 0; j < 4; ++j) {
        float p = exp2f((st[mt][j] - m_new) * sc);
        lsum += p;
        pb[mt][j] = f2bf(p);
      }
    lsum += __shfl_xor(lsum, 16);
    lsum += __shfl_xor(lsum, 32);
    const float alpha = exp2f((m_run - m_new) * sc);
    l_run = l_run * alpha + lsum;
    m_run = m_new;

    // write P: Ps[wave][q=lq][key = mt*16 + g*4 + j]
#pragma unroll
    for (int mt = 0; mt < 4; ++mt) {
      short4v pk;
      pk[0] = (short)pb[mt][0]; pk[1] = (short)pb[mt][1];
      pk[2] = (short)pb[mt][2]; pk[3] = (short)pb[mt][3];
      *(short4v*)(&Ps[wave][lq][mt * 16 + g * 4]) = pk;
    }

    // rescale O rows (O row q = g*4 + j in C layout; stats live at lane q)
    const float a0 = __shfl(alpha, g * 4 + 0);
    const float a1 = __shfl(alpha, g * 4 + 1);
    const float a2 = __shfl(alpha, g * 4 + 2);
    const float a3 = __shfl(alpha, g * 4 + 3);
#pragma unroll
    for (int nt = 0; nt < 8; ++nt) {
      acc_o[nt][0] *= a0; acc_o[nt][1] *= a1;
      acc_o[nt][2] *= a2; acc_o[nt][3] *= a3;
    }

    // PV: O[q][dh] += P[q][key] x V[key][dh]
#pragma unroll
    for (int kk = 0; kk < 2; ++kk) {
      bf16x8 af = *(const bf16x8*)(&Ps[wave][lq][kk * 32 + g * 8]);
#pragma unroll
      for (int nt = 0; nt < 8; ++nt) {
        bf16x8 bfr = *(const bf16x8*)(&Vs[nt * 16 + lq][kk * 32 + g * 8]);
        acc_o[nt] = __builtin_amdgcn_mfma_f32_16x16x32_bf16(af, bfr, acc_o[nt], 0, 0, 0);
      }
    }
  }

  // normalize and store: O[b][s = qb*64+wave*16+g*4+j][h*128 + nt*16 + lq]
  const float i0 = 1.f / __shfl(l_run, g * 4 + 0);
  const float i1 = 1.f / __shfl(l_run, g * 4 + 1);
  const float i2 = 1.f / __shfl(l_run, g * 4 + 2);
  const float i3 = 1.f / __shfl(l_run, g * 4 + 3);
  u16* op = O + ((size_t)b * 2048 + qb * 64 + wave * 16) * 2048 + h * 128;
#pragma unroll
  for (int nt = 0; nt < 8; ++nt) {
    op[(size_t)(g * 4 + 0) * 2048 + nt * 16 + lq] = f2bf(acc_o[nt][0] * i0);
    op[(size_t)(g * 4 + 1) * 2048 + nt * 16 + lq] = f2bf(acc_o[nt][1] * i1);
    op[(size_t)(g * 4 + 2) * 2048 + nt * 16 + lq] = f2bf(acc_o[nt][2] * i2);
    op[(size_t)(g * 4 + 3) * 2048 + nt * 16 + lq] = f2bf(acc_o[nt][3] * i3);
  }
}

// ---------------------------------------------------------------------------
extern "C" void kernel_launch(void* const* d_in, const int* in_sizes, int n_in,
                              void* d_out, int out_size, void* d_ws, size_t ws_size,
                              hipStream_t stream) {
  const void* x  = d_in[0];
  const void* Wq = d_in[1];
  const void* Wk = d_in[2];
  const void* Wv = d_in[3];
  const void* Wo = d_in[4];
  u16* ws = (u16*)d_ws;

  const size_t SLOT = 4194304u;  // 2048*2048 elements
  u16* xb  = ws + 0 * SLOT;   // 2 slots (4096x2048 bf16)
  u16* WqT = ws + 2 * SLOT;
  u16* WkT = ws + 3 * SLOT;
  u16* WvT = ws + 4 * SLOT;
  u16* WoT = ws + 5 * SLOT;
  u16* Qb  = ws + 6 * SLOT;   // 2 slots; attention output aliases this
  u16* Kb  = ws + 8 * SLOT;   // 2 slots
  u16* Vb  = ws + 10 * SLOT;  // 2 slots
  int* flag = (int*)(ws + 12 * SLOT);
  u16* VTd = (u16*)d_out;     // V^T staged in d_out (16.8 MB), dead before final GEMM
  u16* Ab  = Qb;

  sniff_k<<<1, 256, 0, stream>>>((const u16*)x, flag);

  convert_x_k<<<4096, 256, 0, stream>>>(x, xb, flag);  // 8.4M elems, 8/thread
  convert_transpose_k<<<dim3(32, 32), 256, 0, stream>>>(Wq, WqT, flag);
  convert_transpose_k<<<dim3(32, 32), 256, 0, stream>>>(Wk, WkT, flag);
  convert_transpose_k<<<dim3(32, 32), 256, 0, stream>>>(Wv, WvT, flag);
  convert_transpose_k<<<dim3(32, 32), 256, 0, stream>>>(Wo, WoT, flag);

  const dim3 ggrid(16, 32), gblk(256);
  gemm_bt<<<ggrid, gblk, 0, stream>>>(xb, WqT, Qb, 4096, 2048, 2048, nullptr);
  gemm_bt<<<ggrid, gblk, 0, stream>>>(xb, WkT, Kb, 4096, 2048, 2048, nullptr);
  gemm_bt<<<ggrid, gblk, 0, stream>>>(xb, WvT, Vb, 4096, 2048, 2048, nullptr);

  transpose_k<<<dim3(32, 32, 2), 256, 0, stream>>>(Vb, VTd);  // per-batch V^T

  attn_kernel<<<dim3(32, 16, 2), dim3(256), 0, stream>>>(Qb, Kb, VTd, Ab);

  gemm_bt<<<ggrid, gblk, 0, stream>>>(Ab, WoT, d_out, 4096, 2048, 2048, flag);
}